// Round 1
// baseline (1615.144 us; speedup 1.0000x reference)
//
#include <hip/hip_runtime.h>
#include <math.h>

#define D 128
constexpr int ROWCH = 20;   // row chunks for deterministic column sum

// ---------------- kernel 1a: partial column sums of motif ----------------
__global__ __launch_bounds__(256) void colsum_kernel(const float* __restrict__ M,
                                                     float* __restrict__ degP, int N) {
    int j = blockIdx.x * 256 + threadIdx.x;
    int t = blockIdx.y;
    int chunk = (N + ROWCH - 1) / ROWCH;
    int i0 = t * chunk, i1 = min(N, i0 + chunk);
    if (j >= N) return;
    float s = 0.f;
    for (int i = i0; i < i1; i++) s += M[(size_t)i * N + j];
    degP[(size_t)t * N + j] = s;
}

// ---------------- kernel 1b: deg -> dinv (deterministic fixed-order sum) ----------------
__global__ __launch_bounds__(256) void dinv_kernel(const float* __restrict__ degP,
                                                   float* __restrict__ dinv, int N) {
    int j = blockIdx.x * 256 + threadIdx.x;
    if (j >= N) return;
    float s = 1.0f;  // + identity
    for (int t = 0; t < ROWCH; t++) s += degP[(size_t)t * N + j];
    dinv[j] = (s > 0.f) ? (1.0f / sqrtf(s)) : 0.f;
}

// ---------------- kernel 2: z[i][d] = dinv[i] * (x @ W^T)[i][d] ----------------
// W row d held in registers per thread (128 threads, thread = d).
__global__ __launch_bounds__(128) void yz_kernel(const float* __restrict__ x,
                                                 const float* __restrict__ W,
                                                 const float* __restrict__ dinv,
                                                 float* __restrict__ Z, int N) {
    __shared__ float xs[D];
    int tid = threadIdx.x;  // = d
    float4 wr[32];
#pragma unroll
    for (int k = 0; k < 32; k++) wr[k] = *(const float4*)&W[(size_t)tid * D + k * 4];
    for (int i = blockIdx.x; i < N; i += gridDim.x) {
        if (tid < 32) *(float4*)&xs[tid * 4] = *(const float4*)&x[(size_t)i * D + tid * 4];
        __syncthreads();
        float acc = 0.f;
#pragma unroll
        for (int k = 0; k < 32; k++) {
            acc = fmaf(wr[k].x, xs[k * 4 + 0], acc);
            acc = fmaf(wr[k].y, xs[k * 4 + 1], acc);
            acc = fmaf(wr[k].z, xs[k * 4 + 2], acc);
            acc = fmaf(wr[k].w, xs[k * 4 + 3], acc);
        }
        Z[(size_t)i * D + tid] = dinv[i] * acc;
        __syncthreads();
    }
}

// ---------------- kernel 3: S_partial[p] = (M^T @ Z) over i-chunk p ----------------
// J-tile = 64 columns, 128 threads, per-thread 4j x 16d accumulators.
#define JT 64
#define KI 32
__global__ __launch_bounds__(128) void gemm_kernel(const float* __restrict__ M,
                                                   const float* __restrict__ Z,
                                                   float* __restrict__ P,
                                                   int N, int nsplit) {
    __shared__ float Ms[KI][JT];
    __shared__ float Zs[KI][D];
    int tid = threadIdx.x;
    int jt = blockIdx.x;
    int p = blockIdx.y;
    int j0 = jt * JT;
    int chunk = (N + nsplit - 1) / nsplit;
    int i0 = p * chunk, i1 = min(N, i0 + chunk);
    int tj = tid >> 3;        // 0..15 -> 4 cols each
    int td = tid & 7;         // 0..7  -> 16 d each
    int d0 = td * 16;
    int tj4 = tj * 4;

    float acc[4][16];
#pragma unroll
    for (int a = 0; a < 4; a++)
#pragma unroll
        for (int b = 0; b < 16; b++) acc[a][b] = 0.f;

    for (int ib = i0; ib < i1; ib += KI) {
        // stage M tile: 32 x 64 = 512 float4
#pragma unroll
        for (int k = 0; k < 4; k++) {
            int f = tid + k * 128;
            int row = f >> 4;
            int c4 = f & 15;
            int gi = ib + row;
            int gj = j0 + c4 * 4;
            float4 v = make_float4(0.f, 0.f, 0.f, 0.f);
            if (gi < i1 && gj + 3 < N) v = *(const float4*)&M[(size_t)gi * N + gj];
            *(float4*)&Ms[row][c4 * 4] = v;
        }
        // stage Z tile: 32 x 128 = 1024 float4
#pragma unroll
        for (int k = 0; k < 8; k++) {
            int f = tid + k * 128;
            int row = f >> 5;
            int c4 = f & 31;
            int gi = ib + row;
            float4 v = make_float4(0.f, 0.f, 0.f, 0.f);
            if (gi < i1) v = *(const float4*)&Z[(size_t)gi * D + c4 * 4];
            *(float4*)&Zs[row][c4 * 4] = v;
        }
        __syncthreads();
#pragma unroll 4
        for (int ki = 0; ki < KI; ki++) {
            float4 mv = *(float4*)&Ms[ki][tj4];
            float zr[16];
            *(float4*)&zr[0]  = *(float4*)&Zs[ki][d0];
            *(float4*)&zr[4]  = *(float4*)&Zs[ki][d0 + 4];
            *(float4*)&zr[8]  = *(float4*)&Zs[ki][d0 + 8];
            *(float4*)&zr[12] = *(float4*)&Zs[ki][d0 + 12];
            float ma[4] = {mv.x, mv.y, mv.z, mv.w};
#pragma unroll
            for (int a = 0; a < 4; a++)
#pragma unroll
                for (int b = 0; b < 16; b++) acc[a][b] = fmaf(ma[a], zr[b], acc[a][b]);
        }
        __syncthreads();
    }
    size_t pb = (size_t)p * N;
#pragma unroll
    for (int a = 0; a < 4; a++) {
        int j = j0 + tj4 + a;
        if (j < N) {
            float* pr = P + (pb + j) * D + d0;
#pragma unroll
            for (int b4 = 0; b4 < 4; b4++) {
                float4 v = make_float4(acc[a][b4 * 4], acc[a][b4 * 4 + 1],
                                       acc[a][b4 * 4 + 2], acc[a][b4 * 4 + 3]);
                *(float4*)&pr[b4 * 4] = v;
            }
        }
    }
}

// ---------------- kernel 4: reduce partials, tanh, scores, keys ----------------
__global__ __launch_bounds__(128) void reduce_kernel(const float* __restrict__ P,
                                                     const float* __restrict__ Z,
                                                     const float* __restrict__ dinv,
                                                     const float* __restrict__ bg,
                                                     const float* __restrict__ wsc,
                                                     const float* __restrict__ bsc,
                                                     float* __restrict__ H,
                                                     float* __restrict__ scores_out,
                                                     unsigned int* __restrict__ keys,
                                                     int N, int nsplit) {
    int j = blockIdx.x;
    int d = threadIdx.x;
    size_t jd = (size_t)j * D + d;
    float s = 0.f;
    for (int p = 0; p < nsplit; p++) s += P[((size_t)p * N + j) * D + d];
    float dj = dinv[j];
    float h = tanhf(dj * (s + Z[jd]) + bg[d]);
    H[jd] = h;
    float v = h * wsc[d];
#pragma unroll
    for (int off = 32; off > 0; off >>= 1) v += __shfl_down(v, off, 64);
    __shared__ float ws2[2];
    if ((d & 63) == 0) ws2[d >> 6] = v;
    __syncthreads();
    if (d == 0) {
        float sc = ws2[0] + ws2[1] + bsc[0];
        scores_out[j] = sc;
        unsigned int u = __float_as_uint(sc);
        keys[j] = (u & 0x80000000u) ? ~u : (u | 0x80000000u);
    }
}

// ---------------- kernel 5: exact k-th largest via 4-pass byte radix select ----------------
__global__ __launch_bounds__(256) void radix_select_kernel(const unsigned int* __restrict__ keys,
                                                           unsigned int* __restrict__ misc,
                                                           int N, int K) {
    __shared__ unsigned int hist[256];
    __shared__ unsigned int sh_prefix, sh_mask, sh_rem;
    int tid = threadIdx.x;
    if (tid == 0) { sh_prefix = 0; sh_mask = 0; sh_rem = (unsigned)K; }
    __syncthreads();
    for (int b = 3; b >= 0; b--) {
        hist[tid] = 0;
        __syncthreads();
        unsigned int pre = sh_prefix, msk = sh_mask;
        for (int i = tid; i < N; i += 256) {
            unsigned int k = keys[i];
            if ((k & msk) == pre) atomicAdd(&hist[(k >> (8 * b)) & 0xFFu], 1u);
        }
        __syncthreads();
        if (tid == 0) {
            unsigned int rem = sh_rem;
            int v = 255;
            for (;; v--) {
                unsigned int c = hist[v];
                if (c >= rem || v == 0) break;
                rem -= c;
            }
            sh_rem = rem;
            sh_prefix = pre | ((unsigned)v << (8 * b));
            sh_mask = msk | (0xFFu << (8 * b));
        }
        __syncthreads();
    }
    if (tid == 0) { misc[0] = sh_prefix; misc[1] = sh_rem; }
}

// ---------------- kernel 6: stable index-order compaction (= sorted top_idx) ----------------
__global__ __launch_bounds__(1024) void select_kernel(const unsigned int* __restrict__ keys,
                                                      const unsigned int* __restrict__ misc,
                                                      int* __restrict__ topidx,
                                                      float* __restrict__ out_idx, int N) {
    __shared__ unsigned int wsum[16];
    __shared__ unsigned int base_sel, base_eq;
    int tid = threadIdx.x;
    int w = tid >> 6, lane = tid & 63;
    unsigned long long lmask = (lane == 0) ? 0ull : ((1ull << lane) - 1ull);
    unsigned int tau = misc[0], r = misc[1];
    if (tid == 0) { base_sel = 0; base_eq = 0; }
    __syncthreads();
    int nchunk = (N + 1023) / 1024;
    for (int c = 0; c < nchunk; c++) {
        int i = c * 1024 + tid;
        bool valid = i < N;
        unsigned int k = valid ? keys[i] : 0u;
        bool eq = valid && (k == tau);
        bool gt = valid && (k > tau);
        unsigned long long mb = __ballot(eq);
        unsigned int lp_eq = __popcll(mb & lmask);
        if (lane == 0) wsum[w] = (unsigned)__popcll(mb);
        __syncthreads();
        unsigned int wp = 0, tot_eq = 0;
        for (int t = 0; t < 16; t++) { unsigned v = wsum[t]; if (t < w) wp += v; tot_eq += v; }
        unsigned int eqRank = base_eq + wp + lp_eq;
        bool sel = gt || (eq && eqRank < r);
        __syncthreads();
        unsigned long long ms = __ballot(sel);
        unsigned int lp_s = __popcll(ms & lmask);
        if (lane == 0) wsum[w] = (unsigned)__popcll(ms);
        __syncthreads();
        unsigned int wps = 0, tot_s = 0;
        for (int t = 0; t < 16; t++) { unsigned v = wsum[t]; if (t < w) wps += v; tot_s += v; }
        if (sel) {
            unsigned int pos = base_sel + wps + lp_s;
            topidx[pos] = i;
            out_idx[pos] = (float)i;
        }
        __syncthreads();
        if (tid == 0) { base_sel += tot_s; base_eq += tot_eq; }
        __syncthreads();
    }
}

// ---------------- kernel 7: x_pool gather ----------------
__global__ __launch_bounds__(128) void xpool_kernel(const float* __restrict__ H,
                                                    const int* __restrict__ topidx,
                                                    float* __restrict__ out) {
    int r = blockIdx.x, d = threadIdx.x;
    int idx = topidx[r];
    out[(size_t)r * D + d] = H[(size_t)idx * D + d];
}

// ---------------- kernel 8: adjacency/motif pool gathers ----------------
constexpr int ROWS_PB = 8;
__global__ __launch_bounds__(256) void pool_kernel(const float* __restrict__ A,
                                                   const float* __restrict__ Mo,
                                                   const int* __restrict__ topidx,
                                                   float* __restrict__ outA,
                                                   float* __restrict__ outM, int N, int K) {
    extern __shared__ int idx_s[];
    int tid = threadIdx.x;
    int nrb = (K + ROWS_PB - 1) / ROWS_PB;
    int mat = blockIdx.x / nrb;
    int rb = blockIdx.x % nrb;
    const float* src = mat ? Mo : A;
    float* dst = mat ? outM : outA;
    for (int t = tid; t < K; t += 256) idx_s[t] = topidx[t];
    __syncthreads();
    for (int rr = 0; rr < ROWS_PB; rr++) {
        int r = rb * ROWS_PB + rr;
        if (r >= K) break;
        const float* row = src + (size_t)idx_s[r] * N;
        float* orow = dst + (size_t)r * K;
        for (int c = tid; c < K; c += 256) orow[c] = row[idx_s[c]];
    }
}

extern "C" void kernel_launch(void* const* d_in, const int* in_sizes, int n_in,
                              void* d_out, int out_size, void* d_ws, size_t ws_size,
                              hipStream_t stream) {
    const float* x    = (const float*)d_in[0];
    const float* adj  = (const float*)d_in[1];
    const float* mot  = (const float*)d_in[2];
    const float* Wg   = (const float*)d_in[3];
    const float* bg   = (const float*)d_in[4];
    const float* wsc  = (const float*)d_in[5];
    const float* bsc  = (const float*)d_in[6];
    float* out = (float*)d_out;

    int N = in_sizes[0] / D;          // 10000
    int K = (N + 1) / 2;              // ceil(0.5*N) = 5000
    if (K < 1) K = 1;

    // output offsets (flat concat, all read back as f32)
    size_t o_xpool  = 0;
    size_t o_adj    = (size_t)K * D;
    size_t o_motif  = o_adj + (size_t)K * K;
    size_t o_scores = o_motif + (size_t)K * K;
    size_t o_topidx = o_scores + (size_t)N;

    // workspace layout (float units; all offsets multiple of 4 -> float4-safe)
    float* ws = (float*)d_ws;
    size_t off = 0;
    float* degP = ws + off; off += (size_t)ROWCH * N;
    float* dinv = ws + off; off += (size_t)N;
    float* Z    = ws + off; off += (size_t)N * D;
    float* H    = ws + off; off += (size_t)N * D;
    unsigned int* keys = (unsigned int*)(ws + off); off += (size_t)N;
    unsigned int* misc = (unsigned int*)(ws + off); off += 16;
    int* topidx = (int*)(ws + off); off += (size_t)K;
    float* P    = ws + off;   // nsplit * N * D

    size_t fixed_bytes = off * sizeof(float);
    size_t per_split = (size_t)N * D * sizeof(float);
    int nsplit = 1;
    if (ws_size > fixed_bytes + per_split) {
        size_t avail = (ws_size - fixed_bytes) / per_split;
        nsplit = (int)(avail < 6 ? avail : 6);
        if (nsplit < 1) nsplit = 1;
    }

    int jblocks = (N + 255) / 256;
    colsum_kernel<<<dim3(jblocks, ROWCH), 256, 0, stream>>>(mot, degP, N);
    dinv_kernel<<<jblocks, 256, 0, stream>>>(degP, dinv, N);
    yz_kernel<<<256, 128, 0, stream>>>(x, Wg, dinv, Z, N);
    int numJT = (N + JT - 1) / JT;
    gemm_kernel<<<dim3(numJT, nsplit), 128, 0, stream>>>(mot, Z, P, N, nsplit);
    reduce_kernel<<<N, 128, 0, stream>>>(P, Z, dinv, bg, wsc, bsc, H,
                                         out + o_scores, keys, N, nsplit);
    radix_select_kernel<<<1, 256, 0, stream>>>(keys, misc, N, K);
    select_kernel<<<1, 1024, 0, stream>>>(keys, misc, topidx, out + o_topidx, N);
    xpool_kernel<<<K, 128, 0, stream>>>(H, topidx, out + o_xpool);
    int nrb = (K + ROWS_PB - 1) / ROWS_PB;
    pool_kernel<<<2 * nrb, 256, (size_t)K * sizeof(int), stream>>>(
        adj, mot, topidx, out + o_adj, out + o_motif, N, K);
}